// Round 2
// baseline (26938.522 us; speedup 1.0000x reference)
//
#include <hip/hip_runtime.h>
#include <cstddef>

// Sparse 3D CNN, per-batch-item pipeline to fit workspace (<80 MB).
// Spatial chain per item:
// 50,60,65 -> c1 47,57,62 -> c2 44,54,59 -> p1 40,50,55 -> c3 37,47,52
// -> c4 34,44,49 -> p2 30,40,45 -> c5 27,37,42 -> c6 24,34,39 -> c7 21,31,36
// -> p3 17,27,32 ; flatten 14688 -> FC 1000 -> 1000 -> 1

#define NEGSLOPE 0.01f
#define NINF (-3.0e38f)

__device__ __forceinline__ float lrelu(float v) { return v >= 0.f ? v : NEGSLOPE * v; }

// ---------------- scatter (last-write-wins like numpy), full batch ----------------
__global__ void k_claim(const int* __restrict__ coors, unsigned* __restrict__ claim, int N) {
  int i = blockIdx.x * blockDim.x + threadIdx.x;
  if (i >= N) return;
  int b = coors[4*i], z = coors[4*i+1], y = coors[4*i+2], x = coors[4*i+3];
  int v = ((b*50 + z)*60 + y)*65 + x;
  atomicMax(&claim[v], (unsigned)(i + 1));
}

__global__ void k_scatter(const int* __restrict__ coors, const float* __restrict__ feat,
                          const unsigned* __restrict__ claim,
                          float* __restrict__ x0, float* __restrict__ m0, int N) {
  int i = blockIdx.x * blockDim.x + threadIdx.x;
  if (i >= N) return;
  int b = coors[4*i], z = coors[4*i+1], y = coors[4*i+2], x = coors[4*i+3];
  int v = ((b*50 + z)*60 + y)*65 + x;
  m0[v] = 1.f;
  if (claim[v] == (unsigned)(i + 1)) x0[v] = feat[i];
}

// ---------------- weight repack: w[co][ci][k64] -> wr[k64][ci][co] ----------------
__global__ void k_repack(const float* __restrict__ w, float* __restrict__ wr, int CI, int CO) {
  int i = blockIdx.x * blockDim.x + threadIdx.x;
  int tot = CO * CI * 64;
  if (i >= tot) return;
  int k = i & 63;
  int ci = (i >> 6) % CI;
  int co = i / (64 * CI);
  wr[(k * CI + ci) * CO + co] = w[i];
}

// ---------------- per-item mask dilation (max-pool of mask, window K, VALID) -------
__global__ void k_dilate(const float* __restrict__ m, float* __restrict__ o,
                         int Zi, int Yi, int Xi, int Zo, int Yo, int Xo, int K) {
  int gid = blockIdx.x * blockDim.x + threadIdx.x;
  int tot = Zo * Yo * Xo;
  if (gid >= tot) return;
  int x = gid % Xo; int t = gid / Xo;
  int y = t % Yo;
  int z = t / Yo;
  float mx = 0.f;
  for (int dz = 0; dz < K; dz++)
    for (int dy = 0; dy < K; dy++) {
      const float* row = m + (size_t)(((z + dz)*Yi + y + dy)*Xi + x);
      for (int dx = 0; dx < K; dx++) mx = fmaxf(mx, row[dx]);
    }
  o[gid] = mx;
}

// ------- per-item direct conv, channels-last, thread = 1 out voxel, CO accums -------
template<int CI, int CO>
__global__ void k_conv(const float* __restrict__ in, const float* __restrict__ wr,
                       const float* __restrict__ bias, const float* __restrict__ mo,
                       float* __restrict__ out,
                       int Zi, int Yi, int Xi, int Zo, int Yo, int Xo) {
  int gid = blockIdx.x * blockDim.x + threadIdx.x;
  int tot = Zo * Yo * Xo;
  if (gid >= tot) return;
  int x = gid % Xo; int t = gid / Xo;
  int y = t % Yo;
  int z = t / Yo;

  float acc[CO];
#pragma unroll
  for (int i = 0; i < CO; i++) acc[i] = 0.f;

  bool act = mo[gid] > 0.f;
  if (act) {
#pragma unroll 1
    for (int kz = 0; kz < 4; kz++)
#pragma unroll 1
      for (int ky = 0; ky < 4; ky++)
#pragma unroll 1
        for (int kx = 0; kx < 4; kx++) {
          const float* ip = in + (size_t)(((z + kz)*Yi + (y + ky))*Xi + (x + kx)) * CI;
          const float* wp = wr + (size_t)((kz*4 + ky)*4 + kx) * CI * CO;
          if (CI == 1) {
            float v = ip[0];
#pragma unroll
            for (int co = 0; co < CO; co++) acc[co] += v * wp[co];
          } else {
            for (int ci4 = 0; ci4 < CI/4; ci4++) {
              float4 v = *(const float4*)(ip + ci4*4);
#pragma unroll
              for (int u = 0; u < 4; u++) {
                float vv = (&v.x)[u];
                const float* w = wp + (ci4*4 + u) * CO;
#pragma unroll
                for (int co = 0; co < CO; co++) acc[co] += vv * w[co];
              }
            }
          }
        }
  }
  float* op = out + (size_t)gid * CO;
#pragma unroll
  for (int co = 0; co < CO; co++) {
    float r = act ? (acc[co] + bias[co]) : 0.f;
    op[co] = lrelu(r);
  }
}

// ---------------- per-item separable sparse maxpool (C=32, float4/thread) ----------
__global__ void k_pool_z(const float* __restrict__ in, const float* __restrict__ m,
                         float* __restrict__ out, int Zi, int Yi, int Xi, int Zo) {
  int gid = blockIdx.x * blockDim.x + threadIdx.x;
  int tot = Zo * Yi * Xi * 8;
  if (gid >= tot) return;
  int c4 = gid & 7; int v = gid >> 3;
  int x = v % Xi; int t = v / Xi;
  int y = t % Yi;
  int z = t / Yi;
  float4 acc = {NINF, NINF, NINF, NINF};
  for (int j = 0; j < 5; j++) {
    int vi = ((z + j)*Yi + y)*Xi + x;
    if (m[vi] > 0.f) {
      float4 val = *(const float4*)(in + (size_t)vi*32 + c4*4);
      acc.x = fmaxf(acc.x, val.x); acc.y = fmaxf(acc.y, val.y);
      acc.z = fmaxf(acc.z, val.z); acc.w = fmaxf(acc.w, val.w);
    }
  }
  *(float4*)(out + (size_t)v*32 + c4*4) = acc;
}

__global__ void k_pool_y(const float* __restrict__ in, float* __restrict__ out,
                         int Z, int Yi, int Xi, int Yo) {
  int gid = blockIdx.x * blockDim.x + threadIdx.x;
  int tot = Z * Yo * Xi * 8;
  if (gid >= tot) return;
  int c4 = gid & 7; int v = gid >> 3;
  int x = v % Xi; int t = v / Xi;
  int y = t % Yo;
  int z = t / Yo;
  float4 acc = {NINF, NINF, NINF, NINF};
  for (int j = 0; j < 5; j++) {
    int vi = (z*Yi + y + j)*Xi + x;
    float4 val = *(const float4*)(in + (size_t)vi*32 + c4*4);
    acc.x = fmaxf(acc.x, val.x); acc.y = fmaxf(acc.y, val.y);
    acc.z = fmaxf(acc.z, val.z); acc.w = fmaxf(acc.w, val.w);
  }
  *(float4*)(out + (size_t)v*32 + c4*4) = acc;
}

__global__ void k_pool_x(const float* __restrict__ in, const float* __restrict__ mp,
                         float* __restrict__ out, int Z, int Y, int Xi, int Xo) {
  int gid = blockIdx.x * blockDim.x + threadIdx.x;
  int tot = Z * Y * Xo * 8;
  if (gid >= tot) return;
  int c4 = gid & 7; int v = gid >> 3;
  int x = v % Xo; int t = v / Xo;
  int y = t % Y;
  int z = t / Y;
  float4 acc = {NINF, NINF, NINF, NINF};
  for (int j = 0; j < 5; j++) {
    int vi = (z*Y + y)*Xi + x + j;
    float4 val = *(const float4*)(in + (size_t)vi*32 + c4*4);
    acc.x = fmaxf(acc.x, val.x); acc.y = fmaxf(acc.y, val.y);
    acc.z = fmaxf(acc.z, val.z); acc.w = fmaxf(acc.w, val.w);
  }
  bool act = mp[v] > 0.f;
  float4 r;
  r.x = act ? acc.x : 0.f; r.y = act ? acc.y : 0.f;
  r.z = act ? acc.z : 0.f; r.w = act ? acc.w : 0.f;
  *(float4*)(out + (size_t)v*32 + c4*4) = r;
}

// ---------------- per-item final pool (C=1, direct 5^3), 21,31,36 -> 17,27,32 ------
__global__ void k_pool3(const float* __restrict__ xin, const float* __restrict__ m,
                        const float* __restrict__ mp, float* __restrict__ out) {
  int gid = blockIdx.x * blockDim.x + threadIdx.x;
  int tot = 17 * 27 * 32;
  if (gid >= tot) return;
  int x = gid & 31; int t = gid >> 5;
  int y = t % 27;
  int z = t / 27;
  float acc = NINF;
  for (int dz = 0; dz < 5; dz++)
    for (int dy = 0; dy < 5; dy++) {
      const float* rowx = xin + (size_t)(((z + dz)*31 + y + dy)*36 + x);
      const float* rowm = m   + (size_t)(((z + dz)*31 + y + dy)*36 + x);
      for (int dx = 0; dx < 5; dx++)
        if (rowm[dx] > 0.f) acc = fmaxf(acc, rowx[dx]);
    }
  out[gid] = (mp[gid] > 0.f) ? acc : 0.f;
}

// ---------------- FC: out(8,Ncol) = lrelu(X(8,K) @ W(K,Ncol) + b), full batch ------
__global__ void k_fc(const float* __restrict__ X, const float* __restrict__ Wm,
                     const float* __restrict__ bias, float* __restrict__ out,
                     int K, int Ncol) {
  __shared__ float sm[16][16][8];
  int cl = threadIdx.x & 15;
  int kt = threadIdx.x >> 4;
  int col = blockIdx.x * 16 + cl;
  float acc[8];
#pragma unroll
  for (int b = 0; b < 8; b++) acc[b] = 0.f;
  if (col < Ncol) {
    for (int k = kt; k < K; k += 16) {
      float w = Wm[(size_t)k * Ncol + col];
#pragma unroll
      for (int b = 0; b < 8; b++) acc[b] += X[b * K + k] * w;
    }
  }
#pragma unroll
  for (int b = 0; b < 8; b++) sm[kt][cl][b] = acc[b];
  __syncthreads();
  if (threadIdx.x < 128) {
    int c = threadIdx.x & 15;
    int b = threadIdx.x >> 4;
    float s = 0.f;
#pragma unroll
    for (int k = 0; k < 16; k++) s += sm[k][c][b];
    int cc = blockIdx.x * 16 + c;
    if (cc < Ncol) {
      s += bias[cc];
      out[b * Ncol + cc] = lrelu(s);
    }
  }
}

// ---------------- host ----------------
static inline int G(int n) { return (n + 255) / 256; }

extern "C" void kernel_launch(void* const* d_in, const int* in_sizes, int n_in,
                              void* d_out, int out_size, void* d_ws, size_t ws_size,
                              hipStream_t stream) {
  const float* feat  = (const float*)d_in[0];
  const int*   coors = (const int*)d_in[1];
  const float* w1 = (const float*)d_in[3];  const float* b1 = (const float*)d_in[4];
  const float* w2 = (const float*)d_in[5];  const float* b2 = (const float*)d_in[6];
  const float* w3 = (const float*)d_in[7];  const float* b3 = (const float*)d_in[8];
  const float* w4 = (const float*)d_in[9];  const float* b4 = (const float*)d_in[10];
  const float* w5 = (const float*)d_in[11]; const float* b5 = (const float*)d_in[12];
  const float* w6 = (const float*)d_in[13]; const float* b6 = (const float*)d_in[14];
  const float* w7 = (const float*)d_in[15]; const float* b7 = (const float*)d_in[16];
  const float* W8 = (const float*)d_in[17]; const float* b8 = (const float*)d_in[18];
  const float* W9 = (const float*)d_in[19]; const float* b9 = (const float*)d_in[20];
  const float* W10= (const float*)d_in[21]; const float* b10= (const float*)d_in[22];
  float* out = (float*)d_out;

  char* ws = (char*)d_ws;
  size_t off = 0;
  auto alloc = [&](size_t nfloats) -> float* {
    float* p = (float*)(ws + off);
    off += ((nfloats * 4 + 1023) / 1024) * 1024;
    return p;
  };

  // full-batch scatter targets (b,z,y,x), C=1
  unsigned* claim = (unsigned*)alloc(1560000);
  float* x0  = alloc(1560000);
  float* m0  = alloc(1560000);
  // per-item ping-pong (reused across all 8 items)
  float* A   = alloc(5315136);   // holds x1 (47*57*62*32), x3, x5, pool temps
  float* Bb  = alloc(4485888);   // holds x2 (44*54*59*32), x4, x6, pool outs
  float* C   = alloc(4078080);   // pool z-pass temp (40*54*59*32)
  // per-item masks (reused across items)
  float* m1  = alloc(166098);
  float* m2  = alloc(140184);
  float* mp1 = alloc(110000);
  float* m3  = alloc(90428);
  float* m4  = alloc(73304);
  float* mp2 = alloc(54000);
  float* m5  = alloc(41958);
  float* m6  = alloc(31824);
  float* m7  = alloc(23436);
  float* mp3 = alloc(14688);
  float* x7  = alloc(23436);
  float* p3  = alloc(117504);    // full batch: 8 * 14688 (FC input)
  float* wr1 = alloc(2048);
  float* wr2 = alloc(65536);
  float* wr3 = alloc(65536);
  float* wr4 = alloc(65536);
  float* wr5 = alloc(65536);
  float* wr6 = alloc(65536);
  float* wr7 = alloc(2048);
  float* h8  = alloc(8000);
  float* h9  = alloc(8000);
  if (off > ws_size) return;  // ~80 MB now; should always fit

  hipMemsetAsync(claim, 0, 1560000 * 4, stream);
  hipMemsetAsync(x0,    0, 1560000 * 4, stream);
  hipMemsetAsync(m0,    0, 1560000 * 4, stream);

  k_repack<<<G(32*1*64),  256, 0, stream>>>(w1, wr1, 1, 32);
  k_repack<<<G(32*32*64), 256, 0, stream>>>(w2, wr2, 32, 32);
  k_repack<<<G(32*32*64), 256, 0, stream>>>(w3, wr3, 32, 32);
  k_repack<<<G(32*32*64), 256, 0, stream>>>(w4, wr4, 32, 32);
  k_repack<<<G(32*32*64), 256, 0, stream>>>(w5, wr5, 32, 32);
  k_repack<<<G(32*32*64), 256, 0, stream>>>(w6, wr6, 32, 32);
  k_repack<<<G(1*32*64),  256, 0, stream>>>(w7, wr7, 32, 1);

  const int N = 80000;
  k_claim  <<<G(N), 256, 0, stream>>>(coors, claim, N);
  k_scatter<<<G(N), 256, 0, stream>>>(coors, feat, claim, x0, m0, N);

  for (int b = 0; b < 8; b++) {
    const float* x0b = x0 + (size_t)b * 195000;
    const float* m0b = m0 + (size_t)b * 195000;
    // c1: 50,60,65 -> 47,57,62
    k_dilate<<<G(166098), 256, 0, stream>>>(m0b, m1, 50,60,65, 47,57,62, 4);
    k_conv<1,32><<<G(166098), 256, 0, stream>>>(x0b, wr1, b1, m1, A, 50,60,65, 47,57,62);
    // c2: -> 44,54,59
    k_dilate<<<G(140184), 256, 0, stream>>>(m1, m2, 47,57,62, 44,54,59, 4);
    k_conv<32,32><<<G(140184), 256, 0, stream>>>(A, wr2, b2, m2, Bb, 47,57,62, 44,54,59);
    // p1: -> 40,50,55
    k_dilate<<<G(110000), 256, 0, stream>>>(m2, mp1, 44,54,59, 40,50,55, 5);
    k_pool_z<<<G(40*54*59*8), 256, 0, stream>>>(Bb, m2, C, 44,54,59, 40);
    k_pool_y<<<G(40*50*59*8), 256, 0, stream>>>(C, A, 40,54,59, 50);
    k_pool_x<<<G(40*50*55*8), 256, 0, stream>>>(A, mp1, Bb, 40,50,59, 55);
    // c3: -> 37,47,52
    k_dilate<<<G(90428), 256, 0, stream>>>(mp1, m3, 40,50,55, 37,47,52, 4);
    k_conv<32,32><<<G(90428), 256, 0, stream>>>(Bb, wr3, b3, m3, A, 40,50,55, 37,47,52);
    // c4: -> 34,44,49
    k_dilate<<<G(73304), 256, 0, stream>>>(m3, m4, 37,47,52, 34,44,49, 4);
    k_conv<32,32><<<G(73304), 256, 0, stream>>>(A, wr4, b4, m4, Bb, 37,47,52, 34,44,49);
    // p2: -> 30,40,45
    k_dilate<<<G(54000), 256, 0, stream>>>(m4, mp2, 34,44,49, 30,40,45, 5);
    k_pool_z<<<G(30*44*49*8), 256, 0, stream>>>(Bb, m4, C, 34,44,49, 30);
    k_pool_y<<<G(30*40*49*8), 256, 0, stream>>>(C, A, 30,44,49, 40);
    k_pool_x<<<G(30*40*45*8), 256, 0, stream>>>(A, mp2, Bb, 30,40,49, 45);
    // c5: -> 27,37,42
    k_dilate<<<G(41958), 256, 0, stream>>>(mp2, m5, 30,40,45, 27,37,42, 4);
    k_conv<32,32><<<G(41958), 256, 0, stream>>>(Bb, wr5, b5, m5, A, 30,40,45, 27,37,42);
    // c6: -> 24,34,39
    k_dilate<<<G(31824), 256, 0, stream>>>(m5, m6, 27,37,42, 24,34,39, 4);
    k_conv<32,32><<<G(31824), 256, 0, stream>>>(A, wr6, b6, m6, Bb, 27,37,42, 24,34,39);
    // c7 (32->1): -> 21,31,36
    k_dilate<<<G(23436), 256, 0, stream>>>(m6, m7, 24,34,39, 21,31,36, 4);
    k_conv<32,1><<<G(23436), 256, 0, stream>>>(Bb, wr7, b7, m7, x7, 24,34,39, 21,31,36);
    // p3: -> 17,27,32
    k_dilate<<<G(14688), 256, 0, stream>>>(m7, mp3, 21,31,36, 17,27,32, 5);
    k_pool3<<<G(14688), 256, 0, stream>>>(x7, m7, mp3, p3 + (size_t)b * 14688);
  }

  // FC head (full batch)
  k_fc<<<63, 256, 0, stream>>>(p3, W8, b8, h8, 14688, 1000);
  k_fc<<<63, 256, 0, stream>>>(h8, W9, b9, h9, 1000, 1000);
  k_fc<<<1,  256, 0, stream>>>(h9, W10, b10, out, 1000, 1);
}